// Round 1
// baseline (513.539 us; speedup 1.0000x reference)
//
#include <hip/hip_runtime.h>
#include <hip/hip_bf16.h>

// ---------------------------------------------------------------------------
// K1: conv1 (3->8, 7x7, valid) + maxpool2 + relu, fused.
// Block: 256 threads = 16x16 pool-output tile, all 8 output channels/thread.
// Grid: (7,7,128).  LDS: input tile 38x38x3 + weights 8*3*49.
// ---------------------------------------------------------------------------
__global__ __launch_bounds__(256) void k1_conv_pool(
    const float* __restrict__ x, const float* __restrict__ w,
    const float* __restrict__ bias, float* __restrict__ out) {
  __shared__ float s_in[3 * 38 * 38];
  __shared__ float s_w[8 * 3 * 49];
  const int b = blockIdx.z;
  const int PX0 = blockIdx.x * 16, PY0 = blockIdx.y * 16;
  const int X0 = PX0 * 2, Y0 = PY0 * 2;
  const int tid = threadIdx.x;

  for (int idx = tid; idx < 3 * 38 * 38; idx += 256) {
    int c = idx / (38 * 38), rem = idx % (38 * 38);
    int iy = rem / 38, ixx = rem % 38;
    int gy = Y0 + iy, gxx = X0 + ixx;
    float v = 0.f;
    if (gy < 224 && gxx < 224) v = x[((b * 3 + c) * 224 + gy) * 224 + gxx];
    s_in[idx] = v;
  }
  for (int idx = tid; idx < 1176; idx += 256) s_w[idx] = w[idx];
  __syncthreads();

  const int py = tid >> 4, px = tid & 15;
  float acc[8][4];
#pragma unroll
  for (int o = 0; o < 8; ++o)
    acc[o][0] = acc[o][1] = acc[o][2] = acc[o][3] = 0.f;

  for (int c = 0; c < 3; ++c) {
    for (int ky = 0; ky < 7; ++ky) {
      const float* r0 = &s_in[(c * 38 + 2 * py + ky) * 38 + 2 * px];
      const float* r1 = r0 + 38;
#pragma unroll
      for (int kx = 0; kx < 7; ++kx) {
        float i00 = r0[kx], i01 = r0[kx + 1];
        float i10 = r1[kx], i11 = r1[kx + 1];
        const float* wp = &s_w[c * 49 + ky * 7 + kx];
#pragma unroll
        for (int o = 0; o < 8; ++o) {
          float wv = wp[o * 147];
          acc[o][0] = fmaf(i00, wv, acc[o][0]);
          acc[o][1] = fmaf(i01, wv, acc[o][1]);
          acc[o][2] = fmaf(i10, wv, acc[o][2]);
          acc[o][3] = fmaf(i11, wv, acc[o][3]);
        }
      }
    }
  }

  int opy = PY0 + py, opx = PX0 + px;
  if (opy < 109 && opx < 109) {
#pragma unroll
    for (int o = 0; o < 8; ++o) {
      float m = fmaxf(fmaxf(acc[o][0], acc[o][1]), fmaxf(acc[o][2], acc[o][3]));
      m += bias[o];
      out[((b * 8 + o) * 109 + opy) * 109 + opx] = fmaxf(m, 0.f);
    }
  }
}

// ---------------------------------------------------------------------------
// K2: conv2 (8->10, 5x5, valid) + maxpool2 + relu, fused.
// Block: 192 threads, 169 active = 13x13 pool tile (52 = 4*13, exact).
// Grid: (4,4,128). LDS: input tile 30x30x8 + weights 10*8*25.
// ---------------------------------------------------------------------------
__global__ __launch_bounds__(192) void k2_conv_pool(
    const float* __restrict__ in, const float* __restrict__ w,
    const float* __restrict__ bias, float* __restrict__ out) {
  __shared__ float s_in[8 * 30 * 30];
  __shared__ float s_w[10 * 8 * 25];
  const int b = blockIdx.z;
  const int PX0 = blockIdx.x * 13, PY0 = blockIdx.y * 13;
  const int X0 = PX0 * 2, Y0 = PY0 * 2;
  const int tid = threadIdx.x;

  for (int idx = tid; idx < 8 * 30 * 30; idx += 192) {
    int c = idx / 900, rem = idx % 900;
    int iy = rem / 30, ixx = rem % 30;
    s_in[idx] = in[((b * 8 + c) * 109 + Y0 + iy) * 109 + X0 + ixx];
  }
  for (int idx = tid; idx < 2000; idx += 192) s_w[idx] = w[idx];
  __syncthreads();

  if (tid >= 169) return;
  const int py = tid / 13, px = tid % 13;
  float acc[10][4];
#pragma unroll
  for (int o = 0; o < 10; ++o)
    acc[o][0] = acc[o][1] = acc[o][2] = acc[o][3] = 0.f;

  for (int c = 0; c < 8; ++c) {
    for (int ky = 0; ky < 5; ++ky) {
      const float* r0 = &s_in[(c * 30 + 2 * py + ky) * 30 + 2 * px];
      const float* r1 = r0 + 30;
#pragma unroll
      for (int kx = 0; kx < 5; ++kx) {
        float i00 = r0[kx], i01 = r0[kx + 1];
        float i10 = r1[kx], i11 = r1[kx + 1];
        const float* wp = &s_w[c * 25 + ky * 5 + kx];
#pragma unroll
        for (int o = 0; o < 10; ++o) {
          float wv = wp[o * 200];
          acc[o][0] = fmaf(i00, wv, acc[o][0]);
          acc[o][1] = fmaf(i01, wv, acc[o][1]);
          acc[o][2] = fmaf(i10, wv, acc[o][2]);
          acc[o][3] = fmaf(i11, wv, acc[o][3]);
        }
      }
    }
  }

  int opy = PY0 + py, opx = PX0 + px;
#pragma unroll
  for (int o = 0; o < 10; ++o) {
    float m = fmaxf(fmaxf(acc[o][0], acc[o][1]), fmaxf(acc[o][2], acc[o][3]));
    m += bias[o];
    out[((b * 10 + o) * 52 + opy) * 52 + opx] = fmaxf(m, 0.f);
  }
}

// ---------------------------------------------------------------------------
// K3: fc1 split-K partial GEMM. C[128,32] = xs[128,27040] @ fc1_w[32,27040]^T
// 64 blocks, each owns a 448-wide K slice (7 chunks of 64), writes partial C.
// ---------------------------------------------------------------------------
__global__ __launch_bounds__(256) void k3_fc1_partial(
    const float* __restrict__ xs, const float* __restrict__ w,
    float* __restrict__ part) {
  __shared__ float sA[128 * 64];
  __shared__ float sW[64 * 33];  // padded: bank-conflict-free transpose
  const int p = blockIdx.x;
  const int tid = threadIdx.x;
  const int n = tid & 31, bg = tid >> 5;
  float acc[16];
#pragma unroll
  for (int i = 0; i < 16; ++i) acc[i] = 0.f;

  for (int ch = 0; ch < 7; ++ch) {
    const int k0 = p * 448 + ch * 64;
    __syncthreads();
    for (int idx = tid; idx < 8192; idx += 256) {
      int bb = idx >> 6, k = idx & 63;
      int gk = k0 + k;
      sA[idx] = (gk < 27040) ? xs[bb * 27040 + gk] : 0.f;
    }
    for (int idx = tid; idx < 2048; idx += 256) {
      int nn = idx >> 6, k = idx & 63;
      int gk = k0 + k;
      sW[k * 33 + nn] = (gk < 27040) ? w[nn * 27040 + gk] : 0.f;
    }
    __syncthreads();
    for (int k = 0; k < 64; ++k) {
      float wv = sW[k * 33 + n];
#pragma unroll
      for (int i = 0; i < 16; ++i)
        acc[i] = fmaf(sA[(bg * 16 + i) * 64 + k], wv, acc[i]);
    }
  }
#pragma unroll
  for (int i = 0; i < 16; ++i)
    part[p * 4096 + (bg * 16 + i) * 32 + n] = acc[i];
}

// ---------------------------------------------------------------------------
// K4: reduce 64 partials -> h = relu(C + b1). 16 blocks x 256 = 4096 elems.
// ---------------------------------------------------------------------------
__global__ __launch_bounds__(256) void k4_reduce(
    const float* __restrict__ part, const float* __restrict__ b1,
    float* __restrict__ h) {
  const int e = blockIdx.x * 256 + threadIdx.x;
  float s = 0.f;
  for (int p = 0; p < 64; ++p) s += part[p * 4096 + e];
  s += b1[e & 31];
  h[e] = fmaxf(s, 0.f);
}

// ---------------------------------------------------------------------------
// K5: theta = h @ fc2^T + b2 (recomputed per block, trivial), then fused
// affine_grid + bilinear grid_sample (zeros padding, align_corners=True).
// Grid: (196,1,128), 256 thr; 196*256 = 224*224 exactly.
// ---------------------------------------------------------------------------
__global__ __launch_bounds__(256) void k5_sample(
    const float* __restrict__ x, const float* __restrict__ h,
    const float* __restrict__ w2, const float* __restrict__ b2,
    float* __restrict__ out) {
  __shared__ float th[6];
  const int b = blockIdx.z;
  if (threadIdx.x < 6) {
    int j = threadIdx.x;
    float s = b2[j];
    for (int m = 0; m < 32; ++m) s = fmaf(h[b * 32 + m], w2[j * 32 + m], s);
    th[j] = s;
  }
  __syncthreads();

  const int pix = blockIdx.x * 256 + threadIdx.x;
  const int hh = pix / 224, ww = pix % 224;
  const float step = 2.0f / 223.0f;
  float gx = ww * step - 1.0f, gy = hh * step - 1.0f;
  float tx = th[0] * gx + th[1] * gy + th[2];
  float ty = th[3] * gx + th[4] * gy + th[5];
  float ix = (tx + 1.0f) * 0.5f * 223.0f;
  float iy = (ty + 1.0f) * 0.5f * 223.0f;
  float x0 = floorf(ix), y0 = floorf(iy);
  float x1 = x0 + 1.f, y1 = y0 + 1.f;
  float wx1 = ix - x0, wx0 = x1 - ix;
  float wy1 = iy - y0, wy0 = y1 - iy;
  float w00 = wx0 * wy0, w01 = wx1 * wy0, w10 = wx0 * wy1, w11 = wx1 * wy1;
  bool vx0 = (x0 >= 0.f) && (x0 <= 223.f);
  bool vx1 = (x1 >= 0.f) && (x1 <= 223.f);
  bool vy0 = (y0 >= 0.f) && (y0 <= 223.f);
  bool vy1 = (y1 >= 0.f) && (y1 <= 223.f);
  w00 = (vx0 && vy0) ? w00 : 0.f;
  w01 = (vx1 && vy0) ? w01 : 0.f;
  w10 = (vx0 && vy1) ? w10 : 0.f;
  w11 = (vx1 && vy1) ? w11 : 0.f;
  int xi0 = (int)fminf(fmaxf(x0, 0.f), 223.f);
  int xi1 = (int)fminf(fmaxf(x1, 0.f), 223.f);
  int yi0 = (int)fminf(fmaxf(y0, 0.f), 223.f);
  int yi1 = (int)fminf(fmaxf(y1, 0.f), 223.f);
#pragma unroll
  for (int c = 0; c < 3; ++c) {
    const float* img = x + (size_t)((b * 3 + c) * 224) * 224;
    float v = img[yi0 * 224 + xi0] * w00 + img[yi0 * 224 + xi1] * w01 +
              img[yi1 * 224 + xi0] * w10 + img[yi1 * 224 + xi1] * w11;
    out[((b * 3 + c) * 224 + hh) * 224 + ww] = v;
  }
}

extern "C" void kernel_launch(void* const* d_in, const int* in_sizes, int n_in,
                              void* d_out, int out_size, void* d_ws,
                              size_t ws_size, hipStream_t stream) {
  const float* x   = (const float*)d_in[0];
  const float* w1  = (const float*)d_in[1];
  const float* b1  = (const float*)d_in[2];
  const float* w2  = (const float*)d_in[3];
  const float* b2  = (const float*)d_in[4];
  const float* fw1 = (const float*)d_in[5];
  const float* fb1 = (const float*)d_in[6];
  const float* fw2 = (const float*)d_in[7];
  const float* fb2 = (const float*)d_in[8];
  float* out = (float*)d_out;

  float* ws   = (float*)d_ws;
  float* out1 = ws;                    // [128,8,109,109]  = 12,166,144 f32
  float* xs   = out1 + 12166144;       // [128,10,52,52]   =  3,461,120 f32
  float* part = xs + 3461120;          // [64,128,32]      =    262,144 f32
  float* hbuf = part + 262144;         // [128,32]         =      4,096 f32

  k1_conv_pool<<<dim3(7, 7, 128), 256, 0, stream>>>(x, w1, b1, out1);
  k2_conv_pool<<<dim3(4, 4, 128), 192, 0, stream>>>(out1, w2, b2, xs);
  k3_fc1_partial<<<64, 256, 0, stream>>>(xs, fw1, part);
  k4_reduce<<<16, 256, 0, stream>>>(part, fb1, hbuf);
  k5_sample<<<dim3(196, 1, 128), 256, 0, stream>>>(x, hbuf, fw2, fb2, out);
}

// Round 2
// 458.631 us; speedup vs baseline: 1.1197x; 1.1197x over previous
//
#include <hip/hip_runtime.h>
#include <hip/hip_bf16.h>

__device__ __forceinline__ void loadrow8(float* r, const float* p) {
#pragma unroll
  for (int i = 0; i < 4; ++i) {
    float2 t = *(const float2*)(p + 2 * i);
    r[2 * i] = t.x; r[2 * i + 1] = t.y;
  }
}
__device__ __forceinline__ void loadrow6(float* r, const float* p) {
#pragma unroll
  for (int i = 0; i < 3; ++i) {
    float2 t = *(const float2*)(p + 2 * i);
    r[2 * i] = t.x; r[2 * i + 1] = t.y;
  }
}

// ---------------------------------------------------------------------------
// K1: conv1 (3->8, 7x7, valid) + maxpool2 + relu, fused.
// 256 thr = 16x16 pool tile. Register-row inner loop, transposed weights.
// ---------------------------------------------------------------------------
__global__ __launch_bounds__(256) void k1_conv_pool(
    const float* __restrict__ x, const float* __restrict__ w,
    const float* __restrict__ bias, float* __restrict__ out) {
  __shared__ float s_in[3 * 38 * 38];
  __shared__ float s_w[147 * 8];  // [(c*49+ky*7+kx)*8 + o]
  const int b = blockIdx.z;
  const int PX0 = blockIdx.x * 16, PY0 = blockIdx.y * 16;
  const int X0 = PX0 * 2, Y0 = PY0 * 2;
  const int tid = threadIdx.x;

  for (int idx = tid; idx < 3 * 38 * 38; idx += 256) {
    int c = idx / (38 * 38), rem = idx % (38 * 38);
    int iy = rem / 38, ixx = rem % 38;
    int gy = Y0 + iy, gxx = X0 + ixx;
    float v = 0.f;
    if (gy < 224 && gxx < 224) v = x[((b * 3 + c) * 224 + gy) * 224 + gxx];
    s_in[idx] = v;
  }
  for (int idx = tid; idx < 1176; idx += 256) {
    int o = idx / 147, r = idx % 147;
    s_w[r * 8 + o] = w[idx];
  }
  __syncthreads();

  const int py = tid >> 4, px = tid & 15;
  float acc[8][4];
#pragma unroll
  for (int o = 0; o < 8; ++o)
    acc[o][0] = acc[o][1] = acc[o][2] = acc[o][3] = 0.f;

  for (int c = 0; c < 3; ++c) {
    const float* base = &s_in[c * 38 * 38 + 2 * px];
    float rows[2][8];
    loadrow8(rows[0], base + (2 * py) * 38);
#pragma unroll
    for (int ky = 0; ky < 7; ++ky) {
      loadrow8(rows[(ky + 1) & 1], base + (2 * py + ky + 1) * 38);
      const float* r0 = rows[ky & 1];
      const float* r1 = rows[(ky + 1) & 1];
#pragma unroll
      for (int kx = 0; kx < 7; ++kx) {
        const float4* wp = (const float4*)&s_w[(c * 49 + ky * 7 + kx) * 8];
        float4 wa = wp[0], wb = wp[1];
        float wv[8] = {wa.x, wa.y, wa.z, wa.w, wb.x, wb.y, wb.z, wb.w};
        float i00 = r0[kx], i01 = r0[kx + 1];
        float i10 = r1[kx], i11 = r1[kx + 1];
#pragma unroll
        for (int o = 0; o < 8; ++o) {
          acc[o][0] = fmaf(i00, wv[o], acc[o][0]);
          acc[o][1] = fmaf(i01, wv[o], acc[o][1]);
          acc[o][2] = fmaf(i10, wv[o], acc[o][2]);
          acc[o][3] = fmaf(i11, wv[o], acc[o][3]);
        }
      }
    }
  }

  int opy = PY0 + py, opx = PX0 + px;
  if (opy < 109 && opx < 109) {
#pragma unroll
    for (int o = 0; o < 8; ++o) {
      float m = fmaxf(fmaxf(acc[o][0], acc[o][1]), fmaxf(acc[o][2], acc[o][3]));
      m += bias[o];
      out[((b * 8 + o) * 109 + opy) * 109 + opx] = fmaxf(m, 0.f);
    }
  }
}

// ---------------------------------------------------------------------------
// K2: conv2 (8->10, 5x5, valid) + maxpool2 + relu, fused. 13x13 pool tile.
// ---------------------------------------------------------------------------
__global__ __launch_bounds__(192) void k2_conv_pool(
    const float* __restrict__ in, const float* __restrict__ w,
    const float* __restrict__ bias, float* __restrict__ out) {
  __shared__ float s_in[8 * 30 * 30];
  __shared__ float s_w[200 * 12];  // [(c*25+ky*5+kx)*12 + o], padded
  const int b = blockIdx.z;
  const int PX0 = blockIdx.x * 13, PY0 = blockIdx.y * 13;
  const int X0 = PX0 * 2, Y0 = PY0 * 2;
  const int tid = threadIdx.x;

  for (int idx = tid; idx < 8 * 30 * 30; idx += 192) {
    int c = idx / 900, rem = idx % 900;
    int iy = rem / 30, ixx = rem % 30;
    s_in[idx] = in[((b * 8 + c) * 109 + Y0 + iy) * 109 + X0 + ixx];
  }
  for (int idx = tid; idx < 2000; idx += 192) {
    int o = idx / 200, r = idx % 200;
    s_w[r * 12 + o] = w[idx];
  }
  __syncthreads();

  if (tid >= 169) return;
  const int py = tid / 13, px = tid % 13;
  float acc[10][4];
#pragma unroll
  for (int o = 0; o < 10; ++o)
    acc[o][0] = acc[o][1] = acc[o][2] = acc[o][3] = 0.f;

  for (int c = 0; c < 8; ++c) {
    const float* base = &s_in[c * 900 + 2 * px];
    float rows[2][6];
    loadrow6(rows[0], base + (2 * py) * 30);
#pragma unroll
    for (int ky = 0; ky < 5; ++ky) {
      loadrow6(rows[(ky + 1) & 1], base + (2 * py + ky + 1) * 30);
      const float* r0 = rows[ky & 1];
      const float* r1 = rows[(ky + 1) & 1];
#pragma unroll
      for (int kx = 0; kx < 5; ++kx) {
        const float* wb = &s_w[(c * 25 + ky * 5 + kx) * 12];
        float4 wa = *(const float4*)wb;
        float4 wc = *(const float4*)(wb + 4);
        float2 wd = *(const float2*)(wb + 8);
        float wv[10] = {wa.x, wa.y, wa.z, wa.w, wc.x, wc.y, wc.z, wc.w, wd.x, wd.y};
        float i00 = r0[kx], i01 = r0[kx + 1];
        float i10 = r1[kx], i11 = r1[kx + 1];
#pragma unroll
        for (int o = 0; o < 10; ++o) {
          acc[o][0] = fmaf(i00, wv[o], acc[o][0]);
          acc[o][1] = fmaf(i01, wv[o], acc[o][1]);
          acc[o][2] = fmaf(i10, wv[o], acc[o][2]);
          acc[o][3] = fmaf(i11, wv[o], acc[o][3]);
        }
      }
    }
  }

  int opy = PY0 + py, opx = PX0 + px;
#pragma unroll
  for (int o = 0; o < 10; ++o) {
    float m = fmaxf(fmaxf(acc[o][0], acc[o][1]), fmaxf(acc[o][2], acc[o][3]));
    m += bias[o];
    out[((b * 10 + o) * 52 + opy) * 52 + opx] = fmaxf(m, 0.f);
  }
}

// ---------------------------------------------------------------------------
// K3: fc1 split-K partial GEMM. C[128,32] = xs[128,27040] @ fc1_w[32,27040]^T
// ---------------------------------------------------------------------------
__global__ __launch_bounds__(256) void k3_fc1_partial(
    const float* __restrict__ xs, const float* __restrict__ w,
    float* __restrict__ part) {
  __shared__ float sA[128 * 64];
  __shared__ float sW[64 * 33];
  const int p = blockIdx.x;
  const int tid = threadIdx.x;
  const int n = tid & 31, bg = tid >> 5;
  float acc[16];
#pragma unroll
  for (int i = 0; i < 16; ++i) acc[i] = 0.f;

  for (int ch = 0; ch < 7; ++ch) {
    const int k0 = p * 448 + ch * 64;
    __syncthreads();
    for (int idx = tid; idx < 8192; idx += 256) {
      int bb = idx >> 6, k = idx & 63;
      int gk = k0 + k;
      sA[idx] = (gk < 27040) ? xs[bb * 27040 + gk] : 0.f;
    }
    for (int idx = tid; idx < 2048; idx += 256) {
      int nn = idx >> 6, k = idx & 63;
      int gk = k0 + k;
      sW[k * 33 + nn] = (gk < 27040) ? w[nn * 27040 + gk] : 0.f;
    }
    __syncthreads();
    for (int k = 0; k < 64; ++k) {
      float wv = sW[k * 33 + n];
#pragma unroll
      for (int i = 0; i < 16; ++i)
        acc[i] = fmaf(sA[(bg * 16 + i) * 64 + k], wv, acc[i]);
    }
  }
#pragma unroll
  for (int i = 0; i < 16; ++i)
    part[p * 4096 + (bg * 16 + i) * 32 + n] = acc[i];
}

__global__ __launch_bounds__(256) void k4_reduce(
    const float* __restrict__ part, const float* __restrict__ b1,
    float* __restrict__ h) {
  const int e = blockIdx.x * 256 + threadIdx.x;
  float s = 0.f;
  for (int p = 0; p < 64; ++p) s += part[p * 4096 + e];
  s += b1[e & 31];
  h[e] = fmaxf(s, 0.f);
}

// ---------------------------------------------------------------------------
// K5: theta (recomputed per block) + fused affine_grid + bilinear sample.
// ---------------------------------------------------------------------------
__global__ __launch_bounds__(256) void k5_sample(
    const float* __restrict__ x, const float* __restrict__ h,
    const float* __restrict__ w2, const float* __restrict__ b2,
    float* __restrict__ out) {
  __shared__ float th[6];
  const int b = blockIdx.z;
  if (threadIdx.x < 6) {
    int j = threadIdx.x;
    float s = b2[j];
    for (int m = 0; m < 32; ++m) s = fmaf(h[b * 32 + m], w2[j * 32 + m], s);
    th[j] = s;
  }
  __syncthreads();

  const int pix = blockIdx.x * 256 + threadIdx.x;
  const int hh = pix / 224, ww = pix % 224;
  const float step = 2.0f / 223.0f;
  float gx = ww * step - 1.0f, gy = hh * step - 1.0f;
  float tx = th[0] * gx + th[1] * gy + th[2];
  float ty = th[3] * gx + th[4] * gy + th[5];
  float ix = (tx + 1.0f) * 0.5f * 223.0f;
  float iy = (ty + 1.0f) * 0.5f * 223.0f;
  float x0 = floorf(ix), y0 = floorf(iy);
  float x1 = x0 + 1.f, y1 = y0 + 1.f;
  float wx1 = ix - x0, wx0 = x1 - ix;
  float wy1 = iy - y0, wy0 = y1 - iy;
  float w00 = wx0 * wy0, w01 = wx1 * wy0, w10 = wx0 * wy1, w11 = wx1 * wy1;
  bool vx0 = (x0 >= 0.f) && (x0 <= 223.f);
  bool vx1 = (x1 >= 0.f) && (x1 <= 223.f);
  bool vy0 = (y0 >= 0.f) && (y0 <= 223.f);
  bool vy1 = (y1 >= 0.f) && (y1 <= 223.f);
  w00 = (vx0 && vy0) ? w00 : 0.f;
  w01 = (vx1 && vy0) ? w01 : 0.f;
  w10 = (vx0 && vy1) ? w10 : 0.f;
  w11 = (vx1 && vy1) ? w11 : 0.f;
  int xi0 = (int)fminf(fmaxf(x0, 0.f), 223.f);
  int xi1 = (int)fminf(fmaxf(x1, 0.f), 223.f);
  int yi0 = (int)fminf(fmaxf(y0, 0.f), 223.f);
  int yi1 = (int)fminf(fmaxf(y1, 0.f), 223.f);
#pragma unroll
  for (int c = 0; c < 3; ++c) {
    const float* img = x + (size_t)((b * 3 + c) * 224) * 224;
    float v = img[yi0 * 224 + xi0] * w00 + img[yi0 * 224 + xi1] * w01 +
              img[yi1 * 224 + xi0] * w10 + img[yi1 * 224 + xi1] * w11;
    out[((b * 3 + c) * 224 + hh) * 224 + ww] = v;
  }
}

extern "C" void kernel_launch(void* const* d_in, const int* in_sizes, int n_in,
                              void* d_out, int out_size, void* d_ws,
                              size_t ws_size, hipStream_t stream) {
  const float* x   = (const float*)d_in[0];
  const float* w1  = (const float*)d_in[1];
  const float* b1  = (const float*)d_in[2];
  const float* w2  = (const float*)d_in[3];
  const float* b2  = (const float*)d_in[4];
  const float* fw1 = (const float*)d_in[5];
  const float* fb1 = (const float*)d_in[6];
  const float* fw2 = (const float*)d_in[7];
  const float* fb2 = (const float*)d_in[8];
  float* out = (float*)d_out;

  float* ws   = (float*)d_ws;
  float* out1 = ws;                    // [128,8,109,109]
  float* xs   = out1 + 12166144;       // [128,10,52,52]
  float* part = xs + 3461120;          // [64,128,32]
  float* hbuf = part + 262144;         // [128,32]

  k1_conv_pool<<<dim3(7, 7, 128), 256, 0, stream>>>(x, w1, b1, out1);
  k2_conv_pool<<<dim3(4, 4, 128), 192, 0, stream>>>(out1, w2, b2, xs);
  k3_fc1_partial<<<64, 256, 0, stream>>>(xs, fw1, part);
  k4_reduce<<<16, 256, 0, stream>>>(part, fb1, hbuf);
  k5_sample<<<dim3(196, 1, 128), 256, 0, stream>>>(x, hbuf, fw2, fb2, out);
}

// Round 3
// 347.279 us; speedup vs baseline: 1.4787x; 1.3206x over previous
//
#include <hip/hip_runtime.h>
#include <hip/hip_bf16.h>

__device__ __forceinline__ void loadrow8(float* r, const float* p) {
#pragma unroll
  for (int i = 0; i < 4; ++i) {
    float2 t = *(const float2*)(p + 2 * i);
    r[2 * i] = t.x; r[2 * i + 1] = t.y;
  }
}
__device__ __forceinline__ void loadrow6(float* r, const float* p) {
#pragma unroll
  for (int i = 0; i < 3; ++i) {
    float2 t = *(const float2*)(p + 2 * i);
    r[2 * i] = t.x; r[2 * i + 1] = t.y;
  }
}

// ---------------------------------------------------------------------------
// K1: conv1 (3->8, 7x7) + maxpool2 + relu. 256 thr = 16x16 pool tile.
// Inputs staged in LDS (b64 conflict-free rows); weights via SGPR s_load
// (wave-uniform indices) -> zero weight LDS traffic.
// ---------------------------------------------------------------------------
__global__ __launch_bounds__(256) void k1_conv_pool(
    const float* __restrict__ x, const float* __restrict__ w,
    const float* __restrict__ bias, float* __restrict__ out) {
  __shared__ float s_in[3 * 38 * 38];
  const int b = blockIdx.z;
  const int PX0 = blockIdx.x * 16, PY0 = blockIdx.y * 16;
  const int X0 = PX0 * 2, Y0 = PY0 * 2;
  const int tid = threadIdx.x;

  for (int idx = tid; idx < 3 * 38 * 38; idx += 256) {
    int c = idx / (38 * 38), rem = idx % (38 * 38);
    int iy = rem / 38, ixx = rem % 38;
    int gy = Y0 + iy, gxx = X0 + ixx;
    float v = 0.f;
    if (gy < 224 && gxx < 224) v = x[((b * 3 + c) * 224 + gy) * 224 + gxx];
    s_in[idx] = v;
  }
  __syncthreads();

  const int py = tid >> 4, px = tid & 15;
  float acc[8][4];
#pragma unroll
  for (int o = 0; o < 8; ++o)
    acc[o][0] = acc[o][1] = acc[o][2] = acc[o][3] = 0.f;

  for (int c = 0; c < 3; ++c) {
    const float* base = &s_in[c * 1444 + 2 * px];
    const float* wc = w + c * 49;  // w[o*147 + c*49 + ky*7 + kx]
    float rows[2][8];
    loadrow8(rows[0], base + (2 * py) * 38);
#pragma unroll
    for (int ky = 0; ky < 7; ++ky) {
      loadrow8(rows[(ky + 1) & 1], base + (2 * py + ky + 1) * 38);
      const float* r0 = rows[ky & 1];
      const float* r1 = rows[(ky + 1) & 1];
#pragma unroll
      for (int kx = 0; kx < 7; ++kx) {
        float i00 = r0[kx], i01 = r0[kx + 1];
        float i10 = r1[kx], i11 = r1[kx + 1];
#pragma unroll
        for (int o = 0; o < 8; ++o) {
          float wv = wc[o * 147 + ky * 7 + kx];  // uniform -> s_load
          acc[o][0] = fmaf(i00, wv, acc[o][0]);
          acc[o][1] = fmaf(i01, wv, acc[o][1]);
          acc[o][2] = fmaf(i10, wv, acc[o][2]);
          acc[o][3] = fmaf(i11, wv, acc[o][3]);
        }
      }
    }
  }

  int opy = PY0 + py, opx = PX0 + px;
  if (opy < 109 && opx < 109) {
#pragma unroll
    for (int o = 0; o < 8; ++o) {
      float m = fmaxf(fmaxf(acc[o][0], acc[o][1]), fmaxf(acc[o][2], acc[o][3]));
      m += bias[o];
      out[((b * 8 + o) * 109 + opy) * 109 + opx] = fmaxf(m, 0.f);
    }
  }
}

// ---------------------------------------------------------------------------
// K2: conv2 (8->10, 5x5) + maxpool2 + relu. 13x13 pool tile, scalar weights.
// ---------------------------------------------------------------------------
__global__ __launch_bounds__(192) void k2_conv_pool(
    const float* __restrict__ in, const float* __restrict__ w,
    const float* __restrict__ bias, float* __restrict__ out) {
  __shared__ float s_in[8 * 30 * 30];
  const int b = blockIdx.z;
  const int PX0 = blockIdx.x * 13, PY0 = blockIdx.y * 13;
  const int X0 = PX0 * 2, Y0 = PY0 * 2;
  const int tid = threadIdx.x;

  for (int idx = tid; idx < 8 * 30 * 30; idx += 192) {
    int c = idx / 900, rem = idx % 900;
    int iy = rem / 30, ixx = rem % 30;
    s_in[idx] = in[((b * 8 + c) * 109 + Y0 + iy) * 109 + X0 + ixx];
  }
  __syncthreads();

  if (tid >= 169) return;
  const int py = tid / 13, px = tid % 13;
  float acc[10][4];
#pragma unroll
  for (int o = 0; o < 10; ++o)
    acc[o][0] = acc[o][1] = acc[o][2] = acc[o][3] = 0.f;

  for (int c = 0; c < 8; ++c) {
    const float* base = &s_in[c * 900 + 2 * px];
    const float* wc = w + c * 25;  // w[o*200 + c*25 + ky*5 + kx]
    float rows[2][6];
    loadrow6(rows[0], base + (2 * py) * 30);
#pragma unroll
    for (int ky = 0; ky < 5; ++ky) {
      loadrow6(rows[(ky + 1) & 1], base + (2 * py + ky + 1) * 30);
      const float* r0 = rows[ky & 1];
      const float* r1 = rows[(ky + 1) & 1];
#pragma unroll
      for (int kx = 0; kx < 5; ++kx) {
        float i00 = r0[kx], i01 = r0[kx + 1];
        float i10 = r1[kx], i11 = r1[kx + 1];
#pragma unroll
        for (int o = 0; o < 10; ++o) {
          float wv = wc[o * 200 + ky * 5 + kx];  // uniform -> s_load
          acc[o][0] = fmaf(i00, wv, acc[o][0]);
          acc[o][1] = fmaf(i01, wv, acc[o][1]);
          acc[o][2] = fmaf(i10, wv, acc[o][2]);
          acc[o][3] = fmaf(i11, wv, acc[o][3]);
        }
      }
    }
  }

  int opy = PY0 + py, opx = PX0 + px;
#pragma unroll
  for (int o = 0; o < 10; ++o) {
    float m = fmaxf(fmaxf(acc[o][0], acc[o][1]), fmaxf(acc[o][2], acc[o][3]));
    m += bias[o];
    out[((b * 10 + o) * 52 + opy) * 52 + opx] = fmaxf(m, 0.f);
  }
}

// ---------------------------------------------------------------------------
// K3: fc1 split-K partial GEMM, 256 blocks x 2 chunks of 64.
// A read as float4 over k (broadcast-dedup), W conflict-free b32.
// ---------------------------------------------------------------------------
__global__ __launch_bounds__(256) void k3_fc1_partial(
    const float* __restrict__ xs, const float* __restrict__ w,
    float* __restrict__ part) {
  __shared__ float sA[128 * 64];
  __shared__ float sW[64 * 33];
  const int p = blockIdx.x;
  const int tid = threadIdx.x;
  const int n = tid & 31, bg = tid >> 5;
  float acc[16];
#pragma unroll
  for (int i = 0; i < 16; ++i) acc[i] = 0.f;

  for (int ch = 0; ch < 2; ++ch) {
    const int k0 = p * 128 + ch * 64;
    __syncthreads();
    for (int idx = tid; idx < 8192; idx += 256) {
      int bb = idx >> 6, k = idx & 63;
      int gk = k0 + k;
      sA[idx] = (gk < 27040) ? xs[bb * 27040 + gk] : 0.f;
    }
    for (int idx = tid; idx < 2048; idx += 256) {
      int nn = idx >> 6, k = idx & 63;
      int gk = k0 + k;
      sW[k * 33 + nn] = (gk < 27040) ? w[nn * 27040 + gk] : 0.f;
    }
    __syncthreads();
    for (int k = 0; k < 64; k += 4) {
      float w0 = sW[(k + 0) * 33 + n];
      float w1 = sW[(k + 1) * 33 + n];
      float w2 = sW[(k + 2) * 33 + n];
      float w3 = sW[(k + 3) * 33 + n];
#pragma unroll
      for (int i = 0; i < 16; ++i) {
        float4 a = *(const float4*)&sA[(bg * 16 + i) * 64 + k];
        acc[i] = fmaf(a.x, w0, acc[i]);
        acc[i] = fmaf(a.y, w1, acc[i]);
        acc[i] = fmaf(a.z, w2, acc[i]);
        acc[i] = fmaf(a.w, w3, acc[i]);
      }
    }
  }
#pragma unroll
  for (int i = 0; i < 16; ++i)
    part[p * 4096 + (bg * 16 + i) * 32 + n] = acc[i];
}

__global__ __launch_bounds__(256) void k4_reduce(
    const float* __restrict__ part, const float* __restrict__ b1,
    float* __restrict__ h) {
  const int e = blockIdx.x * 256 + threadIdx.x;
  float s = 0.f;
  for (int p = 0; p < 256; ++p) s += part[p * 4096 + e];
  s += b1[e & 31];
  h[e] = fmaxf(s, 0.f);
}

// ---------------------------------------------------------------------------
// K5: theta (recomputed per block) + fused affine_grid + bilinear sample.
// ---------------------------------------------------------------------------
__global__ __launch_bounds__(256) void k5_sample(
    const float* __restrict__ x, const float* __restrict__ h,
    const float* __restrict__ w2, const float* __restrict__ b2,
    float* __restrict__ out) {
  __shared__ float th[6];
  const int b = blockIdx.z;
  if (threadIdx.x < 6) {
    int j = threadIdx.x;
    float s = b2[j];
    for (int m = 0; m < 32; ++m) s = fmaf(h[b * 32 + m], w2[j * 32 + m], s);
    th[j] = s;
  }
  __syncthreads();

  const int pix = blockIdx.x * 256 + threadIdx.x;
  const int hh = pix / 224, ww = pix % 224;
  const float step = 2.0f / 223.0f;
  float gx = ww * step - 1.0f, gy = hh * step - 1.0f;
  float tx = th[0] * gx + th[1] * gy + th[2];
  float ty = th[3] * gx + th[4] * gy + th[5];
  float ix = (tx + 1.0f) * 0.5f * 223.0f;
  float iy = (ty + 1.0f) * 0.5f * 223.0f;
  float x0 = floorf(ix), y0 = floorf(iy);
  float x1 = x0 + 1.f, y1 = y0 + 1.f;
  float wx1 = ix - x0, wx0 = x1 - ix;
  float wy1 = iy - y0, wy0 = y1 - iy;
  float w00 = wx0 * wy0, w01 = wx1 * wy0, w10 = wx0 * wy1, w11 = wx1 * wy1;
  bool vx0 = (x0 >= 0.f) && (x0 <= 223.f);
  bool vx1 = (x1 >= 0.f) && (x1 <= 223.f);
  bool vy0 = (y0 >= 0.f) && (y0 <= 223.f);
  bool vy1 = (y1 >= 0.f) && (y1 <= 223.f);
  w00 = (vx0 && vy0) ? w00 : 0.f;
  w01 = (vx1 && vy0) ? w01 : 0.f;
  w10 = (vx0 && vy1) ? w10 : 0.f;
  w11 = (vx1 && vy1) ? w11 : 0.f;
  int xi0 = (int)fminf(fmaxf(x0, 0.f), 223.f);
  int xi1 = (int)fminf(fmaxf(x1, 0.f), 223.f);
  int yi0 = (int)fminf(fmaxf(y0, 0.f), 223.f);
  int yi1 = (int)fminf(fmaxf(y1, 0.f), 223.f);
#pragma unroll
  for (int c = 0; c < 3; ++c) {
    const float* img = x + (size_t)((b * 3 + c) * 224) * 224;
    float v = img[yi0 * 224 + xi0] * w00 + img[yi0 * 224 + xi1] * w01 +
              img[yi1 * 224 + xi0] * w10 + img[yi1 * 224 + xi1] * w11;
    out[((b * 3 + c) * 224 + hh) * 224 + ww] = v;
  }
}

extern "C" void kernel_launch(void* const* d_in, const int* in_sizes, int n_in,
                              void* d_out, int out_size, void* d_ws,
                              size_t ws_size, hipStream_t stream) {
  const float* x   = (const float*)d_in[0];
  const float* w1  = (const float*)d_in[1];
  const float* b1  = (const float*)d_in[2];
  const float* w2  = (const float*)d_in[3];
  const float* b2  = (const float*)d_in[4];
  const float* fw1 = (const float*)d_in[5];
  const float* fb1 = (const float*)d_in[6];
  const float* fw2 = (const float*)d_in[7];
  const float* fb2 = (const float*)d_in[8];
  float* out = (float*)d_out;

  float* ws   = (float*)d_ws;
  float* out1 = ws;                    // [128,8,109,109] = 12,166,144 f32
  float* xs   = out1 + 12166144;       // [128,10,52,52]  =  3,461,120 f32
  float* part = xs + 3461120;          // [256,128,32]    =  1,048,576 f32
  float* hbuf = part + 1048576;        // [128,32]

  k1_conv_pool<<<dim3(7, 7, 128), 256, 0, stream>>>(x, w1, b1, out1);
  k2_conv_pool<<<dim3(4, 4, 128), 192, 0, stream>>>(out1, w2, b2, xs);
  k3_fc1_partial<<<256, 256, 0, stream>>>(xs, fw1, part);
  k4_reduce<<<16, 256, 0, stream>>>(part, fb1, hbuf);
  k5_sample<<<dim3(196, 1, 128), 256, 0, stream>>>(x, hbuf, fw2, fb2, out);
}